// Round 10
// baseline (190.370 us; speedup 1.0000x reference)
//
#include <hip/hip_runtime.h>

typedef short bf16x8 __attribute__((ext_vector_type(8)));
typedef float f32x4  __attribute__((ext_vector_type(4)));

__device__ __forceinline__ unsigned short f2bf(float f) {
    unsigned int u = __float_as_uint(f);
    u += 0x7FFFu + ((u >> 16) & 1u);
    return (unsigned short)(u >> 16);
}

// tanh-form GELU: x * sigmoid(2*0.79788456*(x + 0.044715 x^3)). |err| <~5e-4 abs.
__device__ __forceinline__ float gelu_f(float x) {
    float x2 = x * x;
    float u = x * (-1.5957691216f - 0.0713548162f * x2);
    float e = __expf(u);
    return x * __builtin_amdgcn_rcpf(1.0f + e);
}

// ---------- fp32 -> bf16 elementwise ----------
__global__ void cvt_f32_bf16(const float* __restrict__ in,
                             unsigned short* __restrict__ out, int n4) {
    int stride = gridDim.x * blockDim.x;
    for (int i = blockIdx.x * blockDim.x + threadIdx.x; i < n4; i += stride) {
        float4 v = ((const float4*)in)[i];
        ushort4 r;
        r.x = f2bf(v.x); r.y = f2bf(v.y); r.z = f2bf(v.z); r.w = f2bf(v.w);
        ((ushort4*)out)[i] = r;
    }
}

// ---------- W2 [H][O] f32 -> W2T [O][H] bf16 ----------
__global__ void transpose_cvt(const float* __restrict__ in,
                              unsigned short* __restrict__ out, int H, int O) {
    __shared__ float tile[32][33];
    int o0 = blockIdx.x * 32, h0 = blockIdx.y * 32;
    int tx = threadIdx.x, ty = threadIdx.y;
    #pragma unroll
    for (int r = 0; r < 32; r += 8)
        tile[ty + r][tx] = in[(size_t)(h0 + ty + r) * O + o0 + tx];
    __syncthreads();
    #pragma unroll
    for (int r = 0; r < 32; r += 8) {
        int o = ty + r;
        out[(size_t)(o0 + o) * H + h0 + tx] = f2bf(tile[tx][o]);
    }
}

// ============ gemm_8ph: 256xBN tile, BK=64, 8-phase (HK order) =============
// C[M,N] = epi(A[M,K]*B[N,K]^T), 512 thr = 8 waves (2M x 4N), per-wave
// 128 x BN/4 out = acc[8][NREP] f32x4 (NREP = BN/64).
// LDS 128KB: 2 bufs x { Ak0 16K | Ak1 16K | Bk0 16K | Bk1 16K }. B always
// staged as 256 rows (BN=192: rows 192..255 staged-never-read; reads stay
// inside d_ws). 64B rows, 4 16B slots; bank = 16*(row&1) + 4*slot -> XOR
// swizzle uses row bits 1-2: phys_slot = logical ^ ((row>>1)&3) (0 conflicts,
// R7-verified). Inverse on global src (linear LDS dest), forward on ds_read.
// R9: HK phase order — per phase {reads; stage; [P4/P8: vmcnt(4)]; s_barrier;
// lgkmcnt(0); setprio(1); MFMA; setprio(0); s_barrier}. Reads issue BEFORE
// the leading barrier (latency hides under barrier wait); vmcnt gates only
// at P4/P8 (12 loads outstanding, retire oldest 8 = one full tile; never 0).
// Hazards (desk-checked): WAR — each stage target's last reader lgkm'd before
// the preceding trailing barrier; RAW — tile certified by vmcnt(4)+barrier
// >=3 phases after its stage issue (> HBM latency). Tail: k2/k3 clamped to
// NTK-1; clamped stages hit only never-again-read regions, counts uniform.
template <int EPI, int K, int N, int BN>
__global__ __launch_bounds__(512, 2) void gemm_8ph(
    const unsigned short* __restrict__ A,
    const unsigned short* __restrict__ B,
    const float* __restrict__ bias,
    void* __restrict__ Cp) {
    constexpr int NREP = BN / 64;
    __shared__ __align__(16) char lds[131072];
    const int t = threadIdx.x;
    const int w = t >> 6, l = t & 63;
    constexpr int ntiles = N / BN;

    int bid = blockIdx.x, nwg = gridDim.x;
    int wgid = ((nwg & 7) == 0) ? ((bid & 7) * (nwg >> 3) + (bid >> 3)) : bid;
    const int mt = wgid / ntiles, nt = wgid % ntiles;
    const int m0 = mt << 8, n0 = nt * BN;
    const int wr = w >> 2, wc = w & 3;

    // staging: unit u covers prow=u>>2 (0..255), phys slot u&3; logical slot
    // lg = (u&3) ^ ((prow>>1)&3) = (u&3) ^ ((u>>3)&3); global = prow*K + lg*8.
    const int u1 = t + 512;
    const int gu0 = (t >> 2) * K + (((t & 3) ^ ((t >> 3) & 3)) << 3);
    const int gu1 = (u1 >> 2) * K + (((u1 & 3) ^ ((u1 >> 3) & 3)) << 3);
    const unsigned short* Abase = A + (size_t)m0 * K;
    const unsigned short* Bbase = B + (size_t)n0 * K;

#define STAGE(PTR, KT, KS, REG) { \
    const unsigned short* g_ = (PTR) + (KT) * 64 + (KS) * 32; \
    __builtin_amdgcn_global_load_lds( \
        (const __attribute__((address_space(1))) void*)(g_ + gu0), \
        (__attribute__((address_space(3))) void*)(lds + (REG) + t * 16), 16, 0, 0); \
    __builtin_amdgcn_global_load_lds( \
        (const __attribute__((address_space(1))) void*)(g_ + gu1), \
        (__attribute__((address_space(3))) void*)(lds + (REG) + 8192 + t * 16), 16, 0, 0); }
#define PIN() { __builtin_amdgcn_sched_barrier(0); asm volatile("" ::: "memory"); }
#define BARR() { asm volatile("s_barrier" ::: "memory"); \
                 __builtin_amdgcn_sched_barrier(0); }
#define VMC4() { asm volatile("s_waitcnt vmcnt(4)" ::: "memory"); \
                 __builtin_amdgcn_sched_barrier(0); }
#define LGKM() { asm volatile("s_waitcnt lgkmcnt(0)" ::: "memory"); \
                 __builtin_amdgcn_sched_barrier(0); }
#define RDB(RG) { const char* p_ = lds + (RG) + boffb; \
    _Pragma("unroll") \
    for (int ni_ = 0; ni_ < NREP; ++ni_) bv[ni_] = *(const bf16x8*)(p_ + ni_ * 1024); }
#define RDA(RG, MH) { const char* p_ = lds + (RG) + aoffb + (MH) * 4096; \
    av[0] = *(const bf16x8*)(p_);        av[1] = *(const bf16x8*)(p_ + 1024); \
    av[2] = *(const bf16x8*)(p_ + 2048); av[3] = *(const bf16x8*)(p_ + 3072); }
#define MFMAQ(MB) \
    __builtin_amdgcn_s_setprio(1); \
    _Pragma("unroll") \
    for (int mi = 0; mi < 4; ++mi) { \
        _Pragma("unroll") \
        for (int ni = 0; ni < NREP; ++ni) \
            acc[MB * 4 + mi][ni] = __builtin_amdgcn_mfma_f32_16x16x32_bf16( \
                av[mi], bv[ni], acc[MB * 4 + mi][ni], 0, 0, 0); \
    } \
    __builtin_amdgcn_s_setprio(0); \
    __builtin_amdgcn_sched_barrier(0);

    // ds_read: A frag row = wr*128 + mh*64 + mi*16 + lr, slot cR = l>>4,
    // phys = cR ^ ((row>>1)&3) = cR ^ ((lr>>1)&3). B frag row = wc*(BN/4)+ni*16+lr.
    const int cR = l >> 4, lr = l & 15;
    const int swz = (cR ^ ((lr >> 1) & 3)) << 4;
    const int aoffb = (wr * 128 + lr) * 64 + swz;              // + mh*4096 + mi*1024
    const int boffb = 32768 + (wc * (BN / 4) + lr) * 64 + swz; // + ni*1024

    f32x4 acc[8][NREP];
    {
        f32x4 z = {0.f, 0.f, 0.f, 0.f};
        #pragma unroll
        for (int i = 0; i < 8; ++i)
            #pragma unroll
            for (int j = 0; j < NREP; ++j) acc[i][j] = z;
    }
    bf16x8 av[4], bv[NREP];

    constexpr int NTK = K >> 6;        // K-tiles of 64
    constexpr int NT2 = K >> 7;        // main iterations (2 K-tiles each)

    // Regions: buf0 = {A0:0, A1:16384, B0:32768, B1:49152},
    //          buf1 = {A0:65536, A1:81920, B0:98304, B1:114688}.
    // Prologue: stage buf0 tile0 fully + buf1.{A0,B0} tile1, certify buf0.
    STAGE(Abase, 0, 0, 0);             PIN();
    STAGE(Bbase, 0, 0, 32768);         PIN();
    STAGE(Abase, 0, 1, 16384);         PIN();
    STAGE(Bbase, 0, 1, 49152);         PIN();
    STAGE(Abase, 1, 0, 65536);         PIN();
    STAGE(Bbase, 1, 0, 98304);         PIN();
    VMC4(); BARR();                    // buf0 tile0 landed; 4 loads in flight

    for (int tt = 0; tt < NT2; ++tt) {
        const int k1 = 2 * tt + 1;
        const int k2 = (2 * tt + 2 < NTK) ? 2 * tt + 2 : NTK - 1;
        const int k3 = (2 * tt + 3 < NTK) ? 2 * tt + 3 : NTK - 1;
        // P1: read buf0.{B0, A0 mh0}; stage buf1.A1(k1); mfma q0
        RDB(0); RDA(0, 0); PIN();
        STAGE(Abase, k1, 1, 81920); PIN();
        BARR(); LGKM(); MFMAQ(0); BARR();
        // P2: read buf0.A0 mh1; stage buf1.B1(k1); mfma q1
        RDA(0, 1); PIN();
        STAGE(Bbase, k1, 1, 114688); PIN();
        BARR(); LGKM(); MFMAQ(1); BARR();
        // P3: read buf0.{B1, A1 mh0}; stage buf0.A0(k2); mfma q0
        RDB(16384); RDA(16384, 0); PIN();
        STAGE(Abase, k2, 0, 0); PIN();
        BARR(); LGKM(); MFMAQ(0); BARR();
        // P4: read buf0.A1 mh1; stage buf0.B0(k2); CERTIFY buf1 tile k1; mfma q1
        RDA(16384, 1); PIN();
        STAGE(Bbase, k2, 0, 32768); PIN();
        VMC4(); BARR(); LGKM(); MFMAQ(1); BARR();
        // P5: read buf1.{B0, A0 mh0}; stage buf0.A1(k2); mfma q0
        RDB(65536); RDA(65536, 0); PIN();
        STAGE(Abase, k2, 1, 16384); PIN();
        BARR(); LGKM(); MFMAQ(0); BARR();
        // P6: read buf1.A0 mh1; stage buf0.B1(k2); mfma q1
        RDA(65536, 1); PIN();
        STAGE(Bbase, k2, 1, 49152); PIN();
        BARR(); LGKM(); MFMAQ(1); BARR();
        // P7: read buf1.{B1, A1 mh0}; stage buf1.A0(k3); mfma q0
        RDB(81920); RDA(81920, 0); PIN();
        STAGE(Abase, k3, 0, 65536); PIN();
        BARR(); LGKM(); MFMAQ(0); BARR();
        // P8: read buf1.A1 mh1; stage buf1.B0(k3); CERTIFY buf0 tile k2; mfma q1
        RDA(81920, 1); PIN();
        STAGE(Bbase, k3, 0, 98304); PIN();
        VMC4(); BARR(); LGKM(); MFMAQ(1); BARR();
    }
    asm volatile("s_waitcnt vmcnt(0)" ::: "memory");
#undef STAGE
#undef PIN
#undef BARR
#undef VMC4
#undef LGKM
#undef RDB
#undef RDA
#undef MFMAQ

    // Epilogue. C/D frag: col = lane&15, row = (lane>>4)*4 + j  (m89-verified)
    const int colb = n0 + wc * (BN / 4) + lr;
    if constexpr (EPI == 0) {
        unsigned short* Cb = (unsigned short*)Cp;
        float bvs[NREP];
        #pragma unroll
        for (int ni = 0; ni < NREP; ++ni) bvs[ni] = bias[colb + ni * 16];
        #pragma unroll
        for (int mi = 0; mi < 8; ++mi)
            #pragma unroll
            for (int j = 0; j < 4; ++j) {
                size_t row = m0 + wr * 128 + mi * 16 + cR * 4 + j;
                #pragma unroll
                for (int ni = 0; ni < NREP; ++ni) {
                    float v = acc[mi][ni][j] + bvs[ni];
                    Cb[row * N + colb + ni * 16] = f2bf(gelu_f(v));
                }
            }
    } else {
        float* Cf = (float*)Cp;
        #pragma unroll
        for (int mi = 0; mi < 8; ++mi)
            #pragma unroll
            for (int j = 0; j < 4; ++j) {
                size_t row = m0 + wr * 128 + mi * 16 + cR * 4 + j;
                #pragma unroll
                for (int ni = 0; ni < NREP; ++ni)
                    Cf[row * N + colb + ni * 16] = acc[mi][ni][j];
            }
    }
}

extern "C" void kernel_launch(void* const* d_in, const int* in_sizes, int n_in,
                              void* d_out, int out_size, void* d_ws, size_t ws_size,
                              hipStream_t stream) {
    const float* x  = (const float*)d_in[0];   // [T, 768]
    const float* w1 = (const float*)d_in[1];   // [3072, 768]
    const float* b1 = (const float*)d_in[2];   // [3072]
    const float* w2 = (const float*)d_in[3];   // [3072, 768]
    float* out = (float*)d_out;                // [T, 768] fp32

    const int T = 16384, DIN = 768, DH = 3072, DOUT = 768;

    unsigned short* xb  = (unsigned short*)d_ws;            // T*DIN bf16
    unsigned short* w1b = xb  + (size_t)T * DIN;            // DH*DIN bf16 ([N][K])
    unsigned short* w2t = w1b + (size_t)DH * DIN;           // DOUT*DH bf16 ([N][K])
    unsigned short* h   = w2t + (size_t)DOUT * DH;          // CH*DH bf16
    // NOTE: gemm_8ph<...,192> stages 256 B-rows; for the last n-tile this
    // reads 64 rows past w2t, i.e. into h — allocated memory, never consumed.

    size_t fixed = ((size_t)T * DIN + (size_t)DH * DIN + (size_t)DOUT * DH) * 2;
    int CH = T;
    while (CH > 256 && fixed + (size_t)CH * DH * 2 > ws_size) CH >>= 1;

    cvt_f32_bf16<<<2048, 256, 0, stream>>>(x, xb, T * DIN / 4);
    cvt_f32_bf16<<<1024, 256, 0, stream>>>(w1, w1b, DH * DIN / 4);
    transpose_cvt<<<dim3(DOUT / 32, DH / 32), dim3(32, 8), 0, stream>>>(w2, w2t, DH, DOUT);

    for (int c0 = 0; c0 < T; c0 += CH) {
        // h = GELU(x_chunk * W1^T + b)      M=CH, N=DH=3072, K=DIN=768, BN=256
        gemm_8ph<0, 768, 3072, 256><<<(CH / 256) * (DH / 256), 512, 0, stream>>>(
            xb + (size_t)c0 * DIN, w1b, b1, h);
        // out_chunk = h * W2T^T             M=CH, N=DOUT=768, K=DH=3072, BN=192
        gemm_8ph<1, 3072, 768, 192><<<(CH / 256) * (DOUT / 192), 512, 0, stream>>>(
            h, w2t, b1, out + (size_t)c0 * DOUT);
    }
}

// Round 12
// 185.794 us; speedup vs baseline: 1.0246x; 1.0246x over previous
//
#include <hip/hip_runtime.h>

typedef short bf16x8 __attribute__((ext_vector_type(8)));
typedef float f32x4  __attribute__((ext_vector_type(4)));

__device__ __forceinline__ unsigned short f2bf(float f) {
    unsigned int u = __float_as_uint(f);
    u += 0x7FFFu + ((u >> 16) & 1u);
    return (unsigned short)(u >> 16);
}

// tanh-form GELU: x * sigmoid(2*0.79788456*(x + 0.044715 x^3)). |err| <~5e-4 abs.
__device__ __forceinline__ float gelu_f(float x) {
    float x2 = x * x;
    float u = x * (-1.5957691216f - 0.0713548162f * x2);
    float e = __expf(u);
    return x * __builtin_amdgcn_rcpf(1.0f + e);
}

// ---------- fused prep: x cvt + w1 cvt + w2 transpose (one launch) ----------
// 2304 blocks x 256 thr. Block b: one 32x32 w2-transpose tile (o=b%24, h=b/24)
// + grid-stride float4 cvt over [x | w1].
__global__ void prep_all(const float* __restrict__ x,
                         const float* __restrict__ w1,
                         const float* __restrict__ w2,
                         unsigned short* __restrict__ xb,
                         unsigned short* __restrict__ w1b,
                         unsigned short* __restrict__ w2t) {
    __shared__ float tile[32][33];
    const int b = blockIdx.x, t = threadIdx.x;
    const int tx = t & 31, ty = t >> 5;                   // 32 x 8
    const int o0 = (b % 24) * 32, h0 = (b / 24) * 32;
    #pragma unroll
    for (int r = 0; r < 32; r += 8)
        tile[ty + r][tx] = w2[(size_t)(h0 + ty + r) * 768 + o0 + tx];
    __syncthreads();
    #pragma unroll
    for (int r = 0; r < 32; r += 8) {
        int o = ty + r;
        w2t[(size_t)(o0 + o) * 3072 + h0 + tx] = f2bf(tile[tx][o]);
    }
    constexpr int NX = 16384 * 768 / 4, NW = 3072 * 768 / 4;
    const int stride = gridDim.x * 256;
    for (int i = b * 256 + t; i < NX + NW; i += stride) {
        const float4 v = (i < NX) ? ((const float4*)x)[i] : ((const float4*)w1)[i - NX];
        ushort4 r;
        r.x = f2bf(v.x); r.y = f2bf(v.y); r.z = f2bf(v.z); r.w = f2bf(v.w);
        if (i < NX) ((ushort4*)xb)[i] = r; else ((ushort4*)w1b)[i - NX] = r;
    }
}

// ============ gemm_m4: 256xBN tile, BK=64, merged 4-phase, counted vmcnt ====
// C[M,N] = epi(A[M,K]*B[N,K]^T), 512 thr = 8 waves (2M x 4N), per-wave
// 128 x BN/4 = acc[8][NREP] f32x4 (NREP = BN/64).
// LDS 128KB: 2 bufs x { A0 16K | A1 16K | B0 16K | B1 16K } (k-half regions).
// B always staged as 256 rows (BN=192: rows 192..255 staged-never-read;
// global reads stay inside d_ws). 64B rows, 4 16B slots; bank = 16*(row&1) +
// 4*slot -> XOR swizzle phys_slot = logical ^ ((row>>1)&3) (R7-verified, 0
// conflicts). Inverse on global src (linear LDS dest), forward on ds_read.
// Merged 4-phase (R8 pairs fused). Phase = one k-half for ALL 128 wave rows:
// {GATE(vmcnt8+barrier); 12 ds_reads (B + A-mh0 + A-mh1); 2 stages;
// lgkmcnt(0); 32 MFMA}. 4 barriers + 4 lgkm per iter (R8 had 4+8).
// R11 fix: R10's PHASE macro had 7 declared params vs 6-arg call sites ->
// STAGE(KT=1, KS=81920) read ~2.6M elems off-base and stomped live LDS (NaN).
// Corrected 6-arg macro; vmcnt ledger re-verified: 12 outstanding at every
// GATE; retire-4 = exactly the 2 regions the phase reads (X1:A0b0/B0b0,
// X2:A1b0/B1b0, X3:A0b1/B0b1, X4:A1b1/B1b1); WAR - stage target's last
// reader lgkm'd before preceding GATE barrier; RAW - stage->read = 3 phases.
// Tail: k1/k2/k3 clamped to NTK-1; clamped stages hit only dead regions.
template <int EPI, int K, int N, int BN>
__global__ __launch_bounds__(512, 2) void gemm_m4(
    const unsigned short* __restrict__ A,
    const unsigned short* __restrict__ B,
    const float* __restrict__ bias,
    void* __restrict__ Cp) {
    constexpr int NREP = BN / 64;
    __shared__ __align__(16) char lds[131072];
    const int t = threadIdx.x;
    const int w = t >> 6, l = t & 63;
    constexpr int ntiles = N / BN;

    int bid = blockIdx.x, nwg = gridDim.x;
    int wgid = ((nwg & 7) == 0) ? ((bid & 7) * (nwg >> 3) + (bid >> 3)) : bid;
    const int mt = wgid / ntiles, nt = wgid % ntiles;
    const int m0 = mt << 8, n0 = nt * BN;
    const int wr = w >> 2, wc = w & 3;

    // staging: unit u covers prow=u>>2 (0..255), phys slot u&3; logical slot
    // lg = (u&3) ^ ((prow>>1)&3) = (u&3) ^ ((u>>3)&3); global = prow*K + lg*8.
    const int u1 = t + 512;
    const int gu0 = (t >> 2) * K + (((t & 3) ^ ((t >> 3) & 3)) << 3);
    const int gu1 = (u1 >> 2) * K + (((u1 & 3) ^ ((u1 >> 3) & 3)) << 3);
    const unsigned short* Abase = A + (size_t)m0 * K;
    const unsigned short* Bbase = B + (size_t)n0 * K;

#define STAGE(PTR, KT, KS, REG) { \
    const unsigned short* g_ = (PTR) + (KT) * 64 + (KS) * 32; \
    __builtin_amdgcn_global_load_lds( \
        (const __attribute__((address_space(1))) void*)(g_ + gu0), \
        (__attribute__((address_space(3))) void*)(lds + (REG) + t * 16), 16, 0, 0); \
    __builtin_amdgcn_global_load_lds( \
        (const __attribute__((address_space(1))) void*)(g_ + gu1), \
        (__attribute__((address_space(3))) void*)(lds + (REG) + 8192 + t * 16), 16, 0, 0); }
#define PIN() { __builtin_amdgcn_sched_barrier(0); asm volatile("" ::: "memory"); }
#define GATE() { asm volatile("s_waitcnt vmcnt(8)\n\ts_barrier" ::: "memory"); \
                 __builtin_amdgcn_sched_barrier(0); }
#define LGKM() { __builtin_amdgcn_sched_barrier(0); \
                 asm volatile("s_waitcnt lgkmcnt(0)" ::: "memory"); \
                 __builtin_amdgcn_sched_barrier(0); }
#define RDB(RG) { const char* p_ = lds + (RG) + boffb; \
    _Pragma("unroll") \
    for (int ni_ = 0; ni_ < NREP; ++ni_) bv[ni_] = *(const bf16x8*)(p_ + ni_ * 1024); }
#define RDA(RG, MH, DST) { const char* p_ = lds + (RG) + aoffb + (MH) * 4096; \
    DST[0] = *(const bf16x8*)(p_);        DST[1] = *(const bf16x8*)(p_ + 1024); \
    DST[2] = *(const bf16x8*)(p_ + 2048); DST[3] = *(const bf16x8*)(p_ + 3072); }
#define MFMAQ(MB, AV) \
    __builtin_amdgcn_s_setprio(1); \
    _Pragma("unroll") \
    for (int mi = 0; mi < 4; ++mi) { \
        _Pragma("unroll") \
        for (int ni = 0; ni < NREP; ++ni) \
            acc[MB * 4 + mi][ni] = __builtin_amdgcn_mfma_f32_16x16x32_bf16( \
                AV[mi], bv[ni], acc[MB * 4 + mi][ni], 0, 0, 0); \
    } \
    __builtin_amdgcn_s_setprio(0); \
    __builtin_amdgcn_sched_barrier(0);
// Merged phase: read one k-half (B + A both m-halves) from region RG,
// stage A(SK,k-half SS)->RA and B(SKB,k-half SSB)->RA+32768, one lgkm, MFMA.
#define PHASE(RG, SK, SS, RA, SKB, SSB) { \
    GATE(); RDB(RG); RDA(RG, 0, av); RDA(RG, 1, avh); PIN(); \
    STAGE(Abase, SK, SS, RA); PIN(); \
    STAGE(Bbase, SKB, SSB, (RA) + 32768); PIN(); \
    LGKM(); MFMAQ(0, av); MFMAQ(1, avh); }

    // ds_read: A frag row = wr*128 + mh*64 + mi*16 + lr, slot cR = l>>4,
    // phys = cR ^ ((row>>1)&3) = cR ^ ((lr>>1)&3). B frag row = wc*(BN/4)+ni*16+lr.
    const int cR = l >> 4, lr = l & 15;
    const int swz = (cR ^ ((lr >> 1) & 3)) << 4;
    const int aoffb = (wr * 128 + lr) * 64 + swz;              // + mh*4096 + mi*1024
    const int boffb = 32768 + (wc * (BN / 4) + lr) * 64 + swz; // + ni*1024

    f32x4 acc[8][NREP];
    {
        f32x4 z = {0.f, 0.f, 0.f, 0.f};
        #pragma unroll
        for (int i = 0; i < 8; ++i)
            #pragma unroll
            for (int j = 0; j < NREP; ++j) acc[i][j] = z;
    }
    bf16x8 av[4], avh[4], bv[NREP];

    constexpr int NTK = K >> 6;        // K-tiles of 64
    constexpr int NT2 = K >> 7;        // main iterations (2 K-tiles each)

    // Regions: buf0 = {A0:0, A1:16384, B0:32768, B1:49152},
    //          buf1 = {A0:65536, A1:81920, B0:98304, B1:114688}.
    // Prologue order = retirement order.
    STAGE(Abase, 0, 0, 0);             PIN();
    STAGE(Bbase, 0, 0, 32768);         PIN();
    STAGE(Abase, 0, 1, 16384);         PIN();
    STAGE(Bbase, 0, 1, 49152);         PIN();
    STAGE(Abase, 1, 0, 65536);         PIN();
    STAGE(Bbase, 1, 0, 98304);         PIN();

    for (int tt = 0; tt < NT2; ++tt) {
        const int k1 = 2 * tt + 1;
        const int k2 = (2 * tt + 2 < NTK) ? 2 * tt + 2 : NTK - 1;
        const int k3 = (2 * tt + 3 < NTK) ? 2 * tt + 3 : NTK - 1;
        // X1: read buf0 khalf0 (tile 2t);   stage buf1.A1(k1), buf1.B1(k1)
        PHASE(0,     k1, 1, 81920, k1, 1);
        // X2: read buf0 khalf1 (tile 2t);   stage buf0.A0(k2), buf0.B0(k2)
        PHASE(16384, k2, 0, 0,     k2, 0);
        // X3: read buf1 khalf0 (tile 2t+1); stage buf0.A1(k2), buf0.B1(k2)
        PHASE(65536, k2, 1, 16384, k2, 1);
        // X4: read buf1 khalf1 (tile 2t+1); stage buf1.A0(k3), buf1.B0(k3)
        PHASE(81920, k3, 0, 65536, k3, 0);
    }
    asm volatile("s_waitcnt vmcnt(0)" ::: "memory");
#undef STAGE
#undef PIN
#undef GATE
#undef LGKM
#undef RDB
#undef RDA
#undef MFMAQ
#undef PHASE

    // Epilogue. C/D frag: col = lane&15, row = (lane>>4)*4 + j  (m89-verified)
    const int colb = n0 + wc * (BN / 4) + lr;
    if constexpr (EPI == 0) {
        unsigned short* Cb = (unsigned short*)Cp;
        float bvs[NREP];
        #pragma unroll
        for (int ni = 0; ni < NREP; ++ni) bvs[ni] = bias[colb + ni * 16];
        #pragma unroll
        for (int mi = 0; mi < 8; ++mi)
            #pragma unroll
            for (int j = 0; j < 4; ++j) {
                size_t row = m0 + wr * 128 + mi * 16 + cR * 4 + j;
                #pragma unroll
                for (int ni = 0; ni < NREP; ++ni) {
                    float v = acc[mi][ni][j] + bvs[ni];
                    Cb[row * N + colb + ni * 16] = f2bf(gelu_f(v));
                }
            }
    } else {
        float* Cf = (float*)Cp;
        #pragma unroll
        for (int mi = 0; mi < 8; ++mi)
            #pragma unroll
            for (int j = 0; j < 4; ++j) {
                size_t row = m0 + wr * 128 + mi * 16 + cR * 4 + j;
                #pragma unroll
                for (int ni = 0; ni < NREP; ++ni)
                    Cf[row * N + colb + ni * 16] = acc[mi][ni][j];
            }
    }
}

extern "C" void kernel_launch(void* const* d_in, const int* in_sizes, int n_in,
                              void* d_out, int out_size, void* d_ws, size_t ws_size,
                              hipStream_t stream) {
    const float* x  = (const float*)d_in[0];   // [T, 768]
    const float* w1 = (const float*)d_in[1];   // [3072, 768]
    const float* b1 = (const float*)d_in[2];   // [3072]
    const float* w2 = (const float*)d_in[3];   // [3072, 768]
    float* out = (float*)d_out;                // [T, 768] fp32

    const int T = 16384, DIN = 768, DH = 3072, DOUT = 768;

    unsigned short* xb  = (unsigned short*)d_ws;            // T*DIN bf16
    unsigned short* w1b = xb  + (size_t)T * DIN;            // DH*DIN bf16 ([N][K])
    unsigned short* w2t = w1b + (size_t)DH * DIN;           // DOUT*DH bf16 ([N][K])
    unsigned short* h   = w2t + (size_t)DOUT * DH;          // CH*DH bf16
    // NOTE: gemm_m4<...,192> stages 256 B-rows; last n-tile reads 64 rows
    // past w2t into h — allocated, never consumed.

    size_t fixed = ((size_t)T * DIN + (size_t)DH * DIN + (size_t)DOUT * DH) * 2;
    int CH = T;
    while (CH > 256 && fixed + (size_t)CH * DH * 2 > ws_size) CH >>= 1;

    prep_all<<<2304, 256, 0, stream>>>(x, w1, w2, xb, w1b, w2t);

    for (int c0 = 0; c0 < T; c0 += CH) {
        // h = GELU(x_chunk * W1^T + b)      M=CH, N=DH=3072, K=DIN=768, BN=256
        gemm_m4<0, 768, 3072, 256><<<(CH / 256) * (DH / 256), 512, 0, stream>>>(
            xb + (size_t)c0 * DIN, w1b, b1, h);
        // out_chunk = h * W2T^T             M=CH, N=DOUT=768, K=DH=3072, BN=192
        gemm_m4<1, 3072, 768, 192><<<(CH / 256) * (DOUT / 192), 512, 0, stream>>>(
            h, w2t, b1, out + (size_t)c0 * DOUT);
    }
}